// Round 1
// baseline (823.182 us; speedup 1.0000x reference)
//
#include <hip/hip_runtime.h>
#include <math.h>

#define BB 4
#define CCH 128
#define HH 384
#define WW 384

constexpr int TILE_X = 64;
constexpr int TILE_Y = 16;
constexpr int CC = 8;              // channels per staged chunk
constexpr int NCHUNK = CCH / CC;   // 16
constexpr int ROWS = TILE_Y + 2;   // 18 (rows y0 .. y0+17; dy>=0 only)
constexpr int COLS = TILE_X + 4;   // 68 (x0-2 .. x0+65)
constexpr int STR  = 72;           // padded row stride (16B-aligned rows)
#define EPSQ 1e-8f

// 12 forward shifts: (0,1),(0,2), (1,-2..2), (2,-2..2).
// Each unordered neighbor pair {p,q} is visited once with weight sel(p)+sel(q);
// cos/lab are symmetric so this equals the reference's 24 directed shifts.

__global__ __launch_bounds__(256, 3)
void ctx_main(const float* __restrict__ er, const int* __restrict__ seg,
              const int* __restrict__ gt, float* __restrict__ Ssum,
              int* __restrict__ cntArr, int* __restrict__ bndArr)
{
    __shared__ __align__(16) float stage[CC * ROWS * STR];   // 41472 B
    __shared__ __align__(16) float normArr[ROWS * STR];      //  5184 B

    const int tx  = threadIdx.x;           // 0..15 (x groups of 4 px)
    const int ty  = threadIdx.y;           // 0..15 (rows)
    const int tid = ty * 16 + tx;
    const int x0  = blockIdx.x * TILE_X;
    const int y0  = blockIdx.y * TILE_Y;
    const int b   = blockIdx.z;

    // halo-norm pixel assignment (200 halo pixels: bottom 2 rows + x edges)
    int h_r = -1, h_a = 0;
    if (tid < 2 * COLS) { h_r = TILE_Y + tid / COLS; h_a = tid % COLS; }
    else if (tid < 2 * COLS + 4 * TILE_Y) {
        int t = tid - 2 * COLS;
        h_r = t >> 2;
        int j = t & 3;
        h_a = (j < 2) ? j : (TILE_X + j);  // 0,1,66,67
    }

    float acc[12][4];
    #pragma unroll
    for (int s = 0; s < 12; ++s)
        #pragma unroll
        for (int i = 0; i < 4; ++i) acc[s][i] = 0.f;
    float nrm[4] = {0.f, 0.f, 0.f, 0.f};
    float haloN = 0.f;

    const float* erB = er + (size_t)b * CCH * HH * WW;

    for (int chunk = 0; chunk < NCHUNK; ++chunk) {
        // ---- stage CC channels of the 18x68 halo tile (clamped loads) ----
        for (int it = tid; it < CC * ROWS * (COLS / 4); it += 256) {
            int c   = it / (ROWS * (COLS / 4));
            int rem = it % (ROWS * (COLS / 4));
            int r   = rem / (COLS / 4);
            int g   = rem % (COLS / 4);
            int gy  = y0 + r; if (gy > HH - 1) gy = HH - 1;
            const float* src = erB + ((size_t)(chunk * CC + c) * HH + gy) * WW;
            int xb = x0 - 2 + 4 * g;
            int xa = min(max(xb    , 0), WW - 1);
            int xb1 = min(max(xb + 1, 0), WW - 1);
            int xc = min(max(xb + 2, 0), WW - 1);
            int xd = min(max(xb + 3, 0), WW - 1);
            float4 v;
            v.x = src[xa]; v.y = src[xb1]; v.z = src[xc]; v.w = src[xd];
            *(float4*)&stage[(c * ROWS + r) * STR + 4 * g] = v;
        }
        __syncthreads();

        // ---- accumulate dots (12 fwd shifts) + own norms ----
        #pragma unroll
        for (int c = 0; c < CC; ++c) {
            const float* r0 = &stage[(c * ROWS + ty) * STR + 4 * tx];
            float4 a0 = *(const float4*)(r0);
            float4 a1 = *(const float4*)(r0 + 4);
            float4 b0 = *(const float4*)(r0 + STR);
            float4 b1 = *(const float4*)(r0 + STR + 4);
            float4 c0 = *(const float4*)(r0 + 2 * STR);
            float4 c1 = *(const float4*)(r0 + 2 * STR + 4);
            float s0[8] = {a0.x,a0.y,a0.z,a0.w,a1.x,a1.y,a1.z,a1.w};
            float s1[8] = {b0.x,b0.y,b0.z,b0.w,b1.x,b1.y,b1.z,b1.w};
            float s2[8] = {c0.x,c0.y,c0.z,c0.w,c1.x,c1.y,c1.z,c1.w};
            float f[4]  = {s0[2], s0[3], s0[4], s0[5]};
            #pragma unroll
            for (int i = 0; i < 4; ++i) {
                nrm[i]    = fmaf(f[i], f[i],     nrm[i]);
                acc[0][i] = fmaf(f[i], s0[i + 3], acc[0][i]);  // (0,+1)
                acc[1][i] = fmaf(f[i], s0[i + 4], acc[1][i]);  // (0,+2)
                #pragma unroll
                for (int d = 0; d < 5; ++d) {                  // dx = d-2
                    acc[2 + d][i] = fmaf(f[i], s1[i + d], acc[2 + d][i]); // dy=1
                    acc[7 + d][i] = fmaf(f[i], s2[i + d], acc[7 + d][i]); // dy=2
                }
            }
        }
        // ---- halo norm partials (values already in LDS) ----
        if (h_r >= 0) {
            #pragma unroll
            for (int c = 0; c < CC; ++c) {
                float v = stage[(c * ROWS + h_r) * STR + h_a];
                haloN = fmaf(v, v, haloN);
            }
        }
        __syncthreads();
    }

    // ---- build packed label/mask tile (reuse stage LDS) + norm tile ----
    int* pkT = (int*)stage;
    for (int it = tid; it < ROWS * COLS; it += 256) {
        int r = it / COLS, a = it % COLS;
        int gy = y0 + r;
        int gx = x0 - 2 + a;
        int pk = 0;
        if (gy < HH && gx >= 0 && gx < WW) {
            int g   = gt[((size_t)b * HH + gy) * WW + gx];
            int gb  = (g == 255) ? 0 : g;
            int s0v = seg[(((size_t)b * 2 + 0) * HH + gy) * WW + gx];
            int s1v = seg[(((size_t)b * 2 + 1) * HH + gy) * WW + gx];
            int s1c = (s1v == 255) ? 0 : s1v;
            bool bnd   = (gb * s1c) > 0;
            bool inter = (gy >= 2 && gy <= HH - 3 && gx >= 2 && gx <= WW - 3);
            pk = (bnd ? 1 : 0) | ((bnd && inter) ? 2 : 0)
               | ((s0v & 255) << 8) | ((s1v & 255) << 16);
        }
        pkT[r * STR + a] = pk;
    }
    #pragma unroll
    for (int i = 0; i < 4; ++i)
        normArr[ty * STR + 4 * tx + 2 + i] = sqrtf(nrm[i]);
    if (h_r >= 0) normArr[h_r * STR + h_a] = sqrtf(haloN);
    __syncthreads();

    // ---- pair epilogue ----
    const float* nr = &normArr[ty * STR + 4 * tx];
    float4 nA = *(const float4*)(nr);
    float4 nB = *(const float4*)(nr + 4);
    float4 nC = *(const float4*)(nr + STR);
    float4 nD = *(const float4*)(nr + STR + 4);
    float4 nE = *(const float4*)(nr + 2 * STR);
    float4 nF = *(const float4*)(nr + 2 * STR + 4);
    float n0[8] = {nA.x,nA.y,nA.z,nA.w,nB.x,nB.y,nB.z,nB.w};
    float n1[8] = {nC.x,nC.y,nC.z,nC.w,nD.x,nD.y,nD.z,nD.w};
    float n2[8] = {nE.x,nE.y,nE.z,nE.w,nF.x,nF.y,nF.z,nF.w};
    const int* pr = (const int*)&pkT[ty * STR + 4 * tx];
    int4 pA = *(const int4*)(pr);
    int4 pB = *(const int4*)(pr + 4);
    int4 pC = *(const int4*)(pr + STR);
    int4 pD = *(const int4*)(pr + STR + 4);
    int4 pE = *(const int4*)(pr + 2 * STR);
    int4 pF = *(const int4*)(pr + 2 * STR + 4);
    int pk0[8] = {pA.x,pA.y,pA.z,pA.w,pB.x,pB.y,pB.z,pB.w};
    int pk1[8] = {pC.x,pC.y,pC.z,pC.w,pD.x,pD.y,pD.z,pD.w};
    int pk2[8] = {pE.x,pE.y,pE.z,pE.w,pF.x,pF.y,pF.z,pF.w};

    float Sth = 0.f; int cth = 0, bth = 0;
    #pragma unroll
    for (int i = 0; i < 4; ++i) {
        int pkP  = pk0[i + 2];
        int selP = (pkP >> 1) & 1;
        cth += selP;
        bth += pkP & 1;
        float nP = fmaxf(n0[i + 2], EPSQ);
        auto doPair = [&](float dot, int pkQ, float nQv) {
            int w = selP + ((pkQ >> 1) & 1);
            if (w) {
                float lab = (float)(((pkP >> 8) & 255) * ((pkQ >> 8) & 255)
                                  + ((pkP >> 16) & 255) * ((pkQ >> 16) & 255));
                float cs = dot / (nP * fmaxf(nQv, EPSQ));
                float d  = cs - lab;
                Sth = fmaf((float)w * d, d, Sth);
            }
        };
        doPair(acc[0][i], pk0[i + 3], n0[i + 3]);
        doPair(acc[1][i], pk0[i + 4], n0[i + 4]);
        #pragma unroll
        for (int d2 = 0; d2 < 5; ++d2) {
            doPair(acc[2 + d2][i], pk1[i + d2], n1[i + d2]);
            doPair(acc[7 + d2][i], pk2[i + d2], n2[i + d2]);
        }
    }

    // ---- reduce + atomics ----
    #pragma unroll
    for (int off = 32; off > 0; off >>= 1) {
        Sth += __shfl_down(Sth, off);
        cth += __shfl_down(cth, off);
        bth += __shfl_down(bth, off);
    }
    if ((tid & 63) == 0) {
        atomicAdd(&Ssum[b], Sth);
        atomicAdd(&cntArr[b], cth);
        atomicAdd(&bndArr[b], bth);
    }
}

__global__ void ctx_init(float* S, int* cnt, int* bnd) {
    int t = threadIdx.x;
    if (t < BB) { S[t] = 0.f; cnt[t] = 0; bnd[t] = 0; }
}

__global__ void ctx_finalize(const float* __restrict__ S, const int* __restrict__ cnt,
                             const int* __restrict__ bnd, float* __restrict__ out) {
    if (threadIdx.x == 0 && blockIdx.x == 0) {
        float tot = 0.f, nv = 0.f;
        for (int b = 0; b < BB; ++b) {
            if (bnd[b] >= 1) {
                float c = fmaxf((float)cnt[b], 1.f);
                tot += S[b] / (24.f * c);
                nv  += 1.f;
            }
        }
        tot = tot / fmaxf(nv, 1.f);
        if (isnan(tot)) tot = 0.f;
        out[0] = tot;
    }
}

extern "C" void kernel_launch(void* const* d_in, const int* in_sizes, int n_in,
                              void* d_out, int out_size, void* d_ws, size_t ws_size,
                              hipStream_t stream) {
    const float* er = (const float*)d_in[0];
    const int* seg  = (const int*)d_in[1];
    const int* gt   = (const int*)d_in[2];
    float* out = (float*)d_out;

    float* S   = (float*)d_ws;
    int*   cnt = (int*)d_ws + BB;
    int*   bnd = (int*)d_ws + 2 * BB;

    ctx_init<<<1, 64, 0, stream>>>(S, cnt, bnd);
    dim3 grid(WW / TILE_X, HH / TILE_Y, BB);
    dim3 block(16, 16);
    ctx_main<<<grid, block, 0, stream>>>(er, seg, gt, S, cnt, bnd);
    ctx_finalize<<<1, 64, 0, stream>>>(S, cnt, bnd, out);
}

// Round 2
// 763.977 us; speedup vs baseline: 1.0775x; 1.0775x over previous
//
#include <hip/hip_runtime.h>
#include <math.h>

#define BB 4
#define CCH 128
#define HH 384
#define WW 384

constexpr int TILE_X = 64;
constexpr int TILE_Y = 8;
constexpr int CC = 8;              // channels per staged chunk
constexpr int NCHUNK = CCH / CC;   // 16
constexpr int ROWS = TILE_Y + 2;   // 10 (rows y0 .. y0+9; dy>=0 only)
constexpr int GR   = 18;           // float4 groups per row
constexpr int STR  = 72;           // floats per row — contiguous (global_load_lds)
constexpr int NSTR = 74;           // norm/label tile stride (bank stagger)
constexpr int NHALO = 168;         // 2*68 bottom rows + 8*4 x-edges
#define EPSQ 1e-8f

// 12 forward shifts: (0,1),(0,2),(1,-2..2),(2,-2..2). Each unordered pair {p,q}
// visited once with weight sel(p)+sel(q) == reference's 24 directed shifts.
// LDS col l <-> global x = x0-4+l (l in [0,72)). Clamps only move ADDRESSES of
// don't-care halo values (any pair touching them has weight 0).

__global__ __launch_bounds__(128, 3)
void ctx_main(const float* __restrict__ er, const int* __restrict__ seg,
              const int* __restrict__ gt, float* __restrict__ Ssum,
              int* __restrict__ cntArr, int* __restrict__ bndArr)
{
    __shared__ __align__(16) float stage[CC * ROWS * STR];   // 23040 B
    __shared__ __align__(16) float normArr[ROWS * NSTR];     //  2960 B

    const int tx  = threadIdx.x;           // 0..15 (x groups of 4 px)
    const int ty  = threadIdx.y;           // 0..7  (rows)
    const int tid = ty * 16 + tx;
    const int x0  = blockIdx.x * TILE_X;
    const int y0  = blockIdx.y * TILE_Y;
    const int b   = blockIdx.z;

    // halo-norm pixel assignment (168 pixels: rows 8,9 cols 2..69; rows 0..7 cols 2,3,68,69)
    int hr[2] = {-1, -1}, hc[2] = {0, 0};
    #pragma unroll
    for (int k = 0; k < 2; ++k) {
        int h = tid + 128 * k;
        if (h < 136) { hr[k] = 8 + h / 68; hc[k] = 2 + h % 68; }
        else if (h < NHALO) {
            int t = h - 136;
            hr[k] = t >> 2;
            int j = t & 3;
            hc[k] = (j < 2) ? (2 + j) : (66 + j);   // 2,3,68,69
        }
    }

    float acc[12][4];
    #pragma unroll
    for (int s = 0; s < 12; ++s)
        #pragma unroll
        for (int i = 0; i < 4; ++i) acc[s][i] = 0.f;
    float nrm[4] = {0.f, 0.f, 0.f, 0.f};
    float haloN[2] = {0.f, 0.f};

    const float* erB = er + (size_t)b * CCH * HH * WW;

    for (int chunk = 0; chunk < NCHUNK; ++chunk) {
        const float* erC = erB + (size_t)chunk * CC * HH * WW;
        // ---- stage CC x 10 x 72 tile straight into LDS (async, lane-linear) ----
        for (int it = tid; it < CC * ROWS * GR; it += 128) {
            int c   = it / (ROWS * GR);
            int rem = it - c * (ROWS * GR);
            int r   = rem / GR;
            int g   = rem - r * GR;
            int gy  = y0 + r; if (gy > HH - 1) gy = HH - 1;
            int gx  = x0 - 4 + 4 * g;
            gx = min(max(gx, 0), WW - 4);            // group clamp; values unused
            const float* src = erC + ((size_t)c * HH + gy) * WW + gx;
            __builtin_amdgcn_global_load_lds(
                (const __attribute__((address_space(1))) void*)src,
                (__attribute__((address_space(3))) void*)(stage + 4 * it),
                16, 0, 0);
        }
        __syncthreads();

        // ---- accumulate dots (12 fwd shifts) + own norms ----
        #pragma unroll
        for (int c = 0; c < CC; ++c) {
            const float* rp = &stage[(c * ROWS + ty) * STR + 4 * tx + 2];
            float s0[8], s1[8], s2[8];
            #pragma unroll
            for (int j = 0; j < 4; ++j) {
                float2 v0 = *(const float2*)(rp + 2 * j);
                float2 v1 = *(const float2*)(rp + STR + 2 * j);
                float2 v2 = *(const float2*)(rp + 2 * STR + 2 * j);
                s0[2*j] = v0.x; s0[2*j+1] = v0.y;
                s1[2*j] = v1.x; s1[2*j+1] = v1.y;
                s2[2*j] = v2.x; s2[2*j+1] = v2.y;
            }
            float f[4] = {s0[2], s0[3], s0[4], s0[5]};
            #pragma unroll
            for (int i = 0; i < 4; ++i) {
                nrm[i]    = fmaf(f[i], f[i],      nrm[i]);
                acc[0][i] = fmaf(f[i], s0[i + 3], acc[0][i]);  // (0,+1)
                acc[1][i] = fmaf(f[i], s0[i + 4], acc[1][i]);  // (0,+2)
                #pragma unroll
                for (int d = 0; d < 5; ++d) {                  // dx = d-2
                    acc[2 + d][i] = fmaf(f[i], s1[i + d], acc[2 + d][i]); // dy=1
                    acc[7 + d][i] = fmaf(f[i], s2[i + d], acc[7 + d][i]); // dy=2
                }
            }
        }
        // ---- halo norm partials (from LDS) ----
        #pragma unroll
        for (int k = 0; k < 2; ++k) if (hr[k] >= 0) {
            #pragma unroll
            for (int c = 0; c < CC; ++c) {
                float v = stage[(c * ROWS + hr[k]) * STR + hc[k]];
                haloN[k] = fmaf(v, v, haloN[k]);
            }
        }
        __syncthreads();
    }

    // ---- build packed label/mask tile (reuse stage LDS) + norm tile ----
    int* pkT = (int*)stage;
    for (int it = tid; it < ROWS * NSTR; it += 128) {
        int r = it / NSTR, a = it - r * NSTR;
        int gy = y0 + r;
        int gx = x0 - 4 + a;
        int pk = 0;
        if (gy < HH && gx >= 0 && gx < WW) {
            int g   = gt[((size_t)b * HH + gy) * WW + gx];
            int gb  = (g == 255) ? 0 : g;
            int s0v = seg[(((size_t)b * 2 + 0) * HH + gy) * WW + gx];
            int s1v = seg[(((size_t)b * 2 + 1) * HH + gy) * WW + gx];
            int s1c = (s1v == 255) ? 0 : s1v;
            bool bnd   = (gb * s1c) > 0;
            bool inter = (gy >= 2 && gy <= HH - 3 && gx >= 2 && gx <= WW - 3);
            pk = (bnd ? 1 : 0) | ((bnd && inter) ? 2 : 0)
               | ((s0v & 255) << 8) | ((s1v & 255) << 16);
        }
        pkT[it] = pk;
    }
    #pragma unroll
    for (int i = 0; i < 4; ++i)
        normArr[ty * NSTR + 4 * tx + 4 + i] = sqrtf(nrm[i]);
    #pragma unroll
    for (int k = 0; k < 2; ++k) if (hr[k] >= 0)
        normArr[hr[k] * NSTR + hc[k]] = sqrtf(haloN[k]);
    __syncthreads();

    // ---- pair epilogue ----
    const float* nr = &normArr[ty * NSTR + 4 * tx + 2];
    const int*   pr = &pkT[ty * NSTR + 4 * tx + 2];
    float n0[8], n1[8], n2[8];
    int   p0[8], p1[8], p2[8];
    #pragma unroll
    for (int j = 0; j < 4; ++j) {
        float2 v0 = *(const float2*)(nr + 2 * j);
        float2 v1 = *(const float2*)(nr + NSTR + 2 * j);
        float2 v2 = *(const float2*)(nr + 2 * NSTR + 2 * j);
        n0[2*j] = v0.x; n0[2*j+1] = v0.y;
        n1[2*j] = v1.x; n1[2*j+1] = v1.y;
        n2[2*j] = v2.x; n2[2*j+1] = v2.y;
        int2 q0 = *(const int2*)(pr + 2 * j);
        int2 q1 = *(const int2*)(pr + NSTR + 2 * j);
        int2 q2 = *(const int2*)(pr + 2 * NSTR + 2 * j);
        p0[2*j] = q0.x; p0[2*j+1] = q0.y;
        p1[2*j] = q1.x; p1[2*j+1] = q1.y;
        p2[2*j] = q2.x; p2[2*j+1] = q2.y;
    }

    float Sth = 0.f; int cth = 0, bth = 0;
    #pragma unroll
    for (int i = 0; i < 4; ++i) {
        int pkP  = p0[i + 2];
        int selP = (pkP >> 1) & 1;
        cth += selP;
        bth += pkP & 1;
        float nP = fmaxf(n0[i + 2], EPSQ);
        auto doPair = [&](float dot, int pkQ, float nQv) {
            int w = selP + ((pkQ >> 1) & 1);
            if (w) {
                float lab = (float)(((pkP >> 8) & 255) * ((pkQ >> 8) & 255)
                                  + ((pkP >> 16) & 255) * ((pkQ >> 16) & 255));
                float cs = dot / (nP * fmaxf(nQv, EPSQ));
                float d  = cs - lab;
                Sth = fmaf((float)w * d, d, Sth);
            }
        };
        doPair(acc[0][i], p0[i + 3], n0[i + 3]);
        doPair(acc[1][i], p0[i + 4], n0[i + 4]);
        #pragma unroll
        for (int d2 = 0; d2 < 5; ++d2) {
            doPair(acc[2 + d2][i], p1[i + d2], n1[i + d2]);
            doPair(acc[7 + d2][i], p2[i + d2], n2[i + d2]);
        }
    }

    // ---- reduce + atomics ----
    #pragma unroll
    for (int off = 32; off > 0; off >>= 1) {
        Sth += __shfl_down(Sth, off);
        cth += __shfl_down(cth, off);
        bth += __shfl_down(bth, off);
    }
    if ((tid & 63) == 0) {
        atomicAdd(&Ssum[b], Sth);
        atomicAdd(&cntArr[b], cth);
        atomicAdd(&bndArr[b], bth);
    }
}

__global__ void ctx_init(float* S, int* cnt, int* bnd) {
    int t = threadIdx.x;
    if (t < BB) { S[t] = 0.f; cnt[t] = 0; bnd[t] = 0; }
}

__global__ void ctx_finalize(const float* __restrict__ S, const int* __restrict__ cnt,
                             const int* __restrict__ bnd, float* __restrict__ out) {
    if (threadIdx.x == 0 && blockIdx.x == 0) {
        float tot = 0.f, nv = 0.f;
        for (int b = 0; b < BB; ++b) {
            if (bnd[b] >= 1) {
                float c = fmaxf((float)cnt[b], 1.f);
                tot += S[b] / (24.f * c);
                nv  += 1.f;
            }
        }
        tot = tot / fmaxf(nv, 1.f);
        if (isnan(tot)) tot = 0.f;
        out[0] = tot;
    }
}

extern "C" void kernel_launch(void* const* d_in, const int* in_sizes, int n_in,
                              void* d_out, int out_size, void* d_ws, size_t ws_size,
                              hipStream_t stream) {
    const float* er = (const float*)d_in[0];
    const int* seg  = (const int*)d_in[1];
    const int* gt   = (const int*)d_in[2];
    float* out = (float*)d_out;

    float* S   = (float*)d_ws;
    int*   cnt = (int*)d_ws + BB;
    int*   bnd = (int*)d_ws + 2 * BB;

    ctx_init<<<1, 64, 0, stream>>>(S, cnt, bnd);
    dim3 grid(WW / TILE_X, HH / TILE_Y, BB);
    dim3 block(16, 8);
    ctx_main<<<grid, block, 0, stream>>>(er, seg, gt, S, cnt, bnd);
    ctx_finalize<<<1, 64, 0, stream>>>(S, cnt, bnd, out);
}